// Round 2
// baseline (4813.963 us; speedup 1.0000x reference)
//
#include <hip/hip_runtime.h>
#include <math.h>

// ---------------------------------------------------------------------------
// RITS forward, round 6: quad-split recurrence. 256 blocks x 1024 threads.
// 64 groups x 4 blocks; group g handles batch rows 4g..4g+3; block s in the
// group owns hidden/jj quarter [64s,64s+64). Per block per step: wg quarter
// 256KB (amortized over 4 rows -> gate weight L2 traffic HALVED vs round 5),
// tdh/wc/hist quarters 16KB r-shared, wf 32KB r-shared. Total L2 traffic
// ~24GB vs ~54GB (theory: aggregate-L2-BW wall ~12-15 TB/s). One 4-way 3KB
// exchange per step (hd quarter f16 + x_h f32 K-partials + alpha d-quarter)
// via device-scope atomics + per-block flag handshake, parity double-buffer.
// B=256, L=256, D=128, H=256.
// ---------------------------------------------------------------------------

namespace {
constexpr int Bn = 256, Ln = 256, Dn = 128, Hn = 256;
constexpr long LD = (long)Ln * Dn;  // 32768

// ws byte offsets
constexpr int OFF_LOSS  = 0;
constexpr int OFF_DEN   = 256;      // 256 f32
constexpr int OFF_BIASG = 2048;     // 1024 f32 [jj][q]
constexpr int OFF_WG    = 8192;     // 262144 dw: [kp<128][jj<256][8]
                                    //   dw 0..3 = W_ih q0..3 pair kp, 4..7 = W_hh
constexpr int OFF_HISTP = 1056768;  // 16384 dw [kp<128][d<128]
constexpr int OFF_TDHP  = 1122304;  // 16384 dw [kp<64][h<256]
constexpr int OFF_WFP   = 1187840;  // 8192 dw  [kp<64][d<128] (diag=0)
constexpr int OFF_WCP   = 1220608;  // 16384 dw [kp<128][d<128]
constexpr int OFF_EXCH  = 1286144;  // 256 blk * 2 parity * 3072 B = 1.5 MB
constexpr int OFF_FLAG  = 2859008;  // 256 flags * 64 B
// exch slot layout (u32 idx): [0..127]=hd quarter [kpl<32][r<4]
//                             [128..255]=alpha quarter [r<4][dl<32]
//                             [256..767]=x_h partial [r<4][d<128]
}  // namespace

typedef _Float16 h2f __attribute__((ext_vector_type(2)));
typedef unsigned int uint32;

__device__ __forceinline__ float fdot2(uint32 a, uint32 b, float c) {
  return __builtin_amdgcn_fdot2(__builtin_bit_cast(h2f, a),
                                __builtin_bit_cast(h2f, b), c, false);
}
__device__ __forceinline__ uint32 packf16(float a, float b) {
  h2f p; p[0] = (_Float16)a; p[1] = (_Float16)b;
  return __builtin_bit_cast(uint32, p);
}
__device__ __forceinline__ unsigned short f16u(float a) {
  _Float16 h = (_Float16)a; return __builtin_bit_cast(unsigned short, h);
}

// ======================= K1: repack + biases + denom ========================
__global__ void rits_prep(const float* __restrict__ td_h_W,
                          const float* __restrict__ hist_W,
                          const float* __restrict__ feat_W,
                          const float* __restrict__ wc_W,
                          const float* __restrict__ W_ih,
                          const float* __restrict__ W_hh,
                          const float* __restrict__ b_ih,
                          const float* __restrict__ b_hh,
                          const float* __restrict__ evalm,
                          char* __restrict__ wsb) {
  const int blk = blockIdx.x, tid = threadIdx.x;
  if (blk < 1248) {
    int idx = blk * 256 + tid;
    if (idx < 262144) {  // wg
      int kp = idx >> 11, rem = idx & 2047, jj = rem >> 3, s8 = rem & 7;
      const float* src = (s8 < 4) ? W_ih : W_hh;
      int q = s8 & 3;
      const float* row = src + (size_t)(q * 256 + jj) * 256 + 2 * kp;
      ((uint32*)(wsb + OFF_WG))[idx] = packf16(row[0], row[1]);
    } else if (idx < 278528) {  // histP
      int i2 = idx - 262144, kp = i2 >> 7, d = i2 & 127;
      ((uint32*)(wsb + OFF_HISTP))[i2] =
          packf16(hist_W[d * 256 + 2 * kp], hist_W[d * 256 + 2 * kp + 1]);
    } else if (idx < 294912) {  // tdhP
      int i2 = idx - 278528, kp = i2 >> 8, h = i2 & 255;
      ((uint32*)(wsb + OFF_TDHP))[i2] =
          packf16(td_h_W[h * 128 + 2 * kp], td_h_W[h * 128 + 2 * kp + 1]);
    } else if (idx < 303104) {  // wfP: [kp<64][d<128], Wf[d][k], diag=0
      int i2 = idx - 294912, kp = i2 >> 7, d = i2 & 127;
      float a = (2 * kp == d) ? 0.f : feat_W[d * 128 + 2 * kp];
      float b = (2 * kp + 1 == d) ? 0.f : feat_W[d * 128 + 2 * kp + 1];
      ((uint32*)(wsb + OFF_WFP))[i2] = packf16(a, b);
    } else if (idx < 319488) {  // wcP
      int i2 = idx - 303104, kp = i2 >> 7, d = i2 & 127;
      ((uint32*)(wsb + OFF_WCP))[i2] =
          packf16(wc_W[d * 256 + 2 * kp], wc_W[d * 256 + 2 * kp + 1]);
    }
  } else if (blk < 1252) {  // biasg
    int i = (blk - 1248) * 256 + tid;
    int jj = i >> 2, q = i & 3;
    ((float*)(wsb + OFF_BIASG))[jj * 4 + q] =
        b_ih[q * 256 + jj] + b_hh[q * 256 + jj];
    if (blk == 1248 && tid == 0) *((float*)(wsb + OFF_LOSS)) = 0.f;
  } else if (blk < 1508) {  // denom per t
    int t = blk - 1252;
    __shared__ float red[256];
    int d = tid & 127, g = tid >> 7;
    float s = 0.f;
    for (int b = g; b < 256; b += 2) s += evalm[(size_t)b * LD + t * 128 + d];
    red[tid] = s;
    __syncthreads();
    for (int o = 128; o > 0; o >>= 1) {
      if (tid < o) red[tid] += red[tid + o];
      __syncthreads();
    }
    if (tid == 0) ((float*)(wsb + OFF_DEN))[t] = red[0] + 1e-5f;
  } else {  // blk == 1508: zero exchange flags (required each launch/replay)
    for (int i = tid; i < 4096; i += 256) ((uint32*)(wsb + OFF_FLAG))[i] = 0u;
  }
}

// ========================== K2: recurrent blocks ============================
__global__ __launch_bounds__(1024, 4) void rits_rec(
    const float* __restrict__ values, const float* __restrict__ masks,
    const float* __restrict__ deltas, const float* __restrict__ evalm,
    const float* __restrict__ td_h_b, const float* __restrict__ td_x_w,
    const float* __restrict__ td_x_b, const float* __restrict__ hist_b,
    const float* __restrict__ feat_b, const float* __restrict__ wc_b,
    char* __restrict__ wsb, float* __restrict__ outp) {
  __shared__ __align__(16) float scratch[16384];  // 64 KB shared partials
  __shared__ float den_s[256], bg_s[256], tdhb_s[64];
  __shared__ float txw_s[128], txb_s[128], hb_s[128], fb_s[128], wcb_s[128];
  __shared__ float hf[4][64], cst[4][64];   // own h-quarter, 4 rows
  __shared__ float xs[4][128], ms[4][128], es[4][128];
  __shared__ float xhp[4][4][128];          // [src-block s][r][d] partials
  __shared__ float xh_s[4][128], al_s[4][128];
  __shared__ uint32 hdP[128 * 4];   // full hd pairs [kp<128][r<4]
  __shared__ uint32 cmP[128 * 4];   // [c_c kp<64 | m kp 64..127][r]
  __shared__ uint32 xcP[64 * 4];    // x_c pairs [kp][r]
  __shared__ uint32 drP[64 * 4];    // deltas pairs [kp][r]
  __shared__ uint32 gxmP[128 * 4];  // [gamma_x kp<64 | m][r]

  const int tid = threadIdx.x;
  const int bid = blockIdx.x;
  const int sh = bid >> 6;    // owned quarter 0..3
  const int grp = bid & 63;   // group: rows 4*grp..4*grp+3
  const size_t b0 = (size_t)grp * 4;
  const uint32* wg = (const uint32*)(wsb + OFF_WG);
  const uint4* histP4 = (const uint4*)(wsb + OFF_HISTP);
  const uint4* tdhP4 = (const uint4*)(wsb + OFF_TDHP);
  const uint4* wfP4 = (const uint4*)(wsb + OFF_WFP);
  const uint4* wcP4 = (const uint4*)(wsb + OFF_WCP);
  char* exch = wsb + OFF_EXCH;
  unsigned int* flg = (unsigned int*)(wsb + OFF_FLAG);

  // -------- preload / init --------
  if (tid < 256) bg_s[tid] = ((const float*)(wsb + OFF_BIASG))[sh * 256 + tid];
  else if (tid < 512) den_s[tid - 256] = ((const float*)(wsb + OFF_DEN))[tid - 256];
  else if (tid < 576) tdhb_s[tid - 512] = td_h_b[sh * 64 + (tid - 512)];
  else if (tid < 704) txw_s[tid - 576] = td_x_w[tid - 576];
  else if (tid < 832) txb_s[tid - 704] = td_x_b[tid - 704];
  else if (tid < 960) hb_s[tid - 832] = hist_b[tid - 832];
  if (tid < 128) fb_s[tid] = feat_b[tid];
  else if (tid < 256) wcb_s[tid - 128] = wc_b[tid - 128];
  else if (tid < 512) ((float*)hf)[tid - 256] = 0.f;
  else if (tid < 768) ((float*)cst)[tid - 512] = 0.f;
  __syncthreads();

  float lacc = 0.f;
  for (int t = 0; t < Ln; ++t) {
    const size_t base = b0 * LD + (size_t)t * 128;
    uint32* mypU = (uint32*)(exch + (size_t)(bid * 2 + (t & 1)) * 3072);

    // ---- A: stage inputs; gamma_x & m pairs (all 4 rows) ----
    if (tid < 512) {
      int d = tid & 127, r = tid >> 7;
      size_t gi = base + (size_t)r * LD + d;
      xs[r][d] = values[gi];
      ms[r][d] = masks[gi];
      es[r][d] = evalm[gi];
    } else {
      int i = tid - 512, kp = i & 127, r = i >> 7;
      size_t gb = base + (size_t)r * LD;
      if (kp < 64) {
        float d0v = deltas[gb + 2 * kp], d1v = deltas[gb + 2 * kp + 1];
        drP[kp * 4 + r] = packf16(d0v, d1v);
        float g0 = __expf(-fmaxf(fmaf(d0v, txw_s[2 * kp], txb_s[2 * kp]), 0.f));
        float g1 = __expf(-fmaxf(fmaf(d1v, txw_s[2 * kp + 1], txb_s[2 * kp + 1]), 0.f));
        gxmP[kp * 4 + r] = packf16(g0, g1);
      } else {
        int k2 = kp - 64;
        gxmP[kp * 4 + r] = packf16(masks[gb + 2 * k2], masks[gb + 2 * k2 + 1]);
      }
    }
    __syncthreads();

    // ---- B: gamma_h partials (own h-quarter) | alpha partials (own d-qtr) --
    if (tid < 128) {  // B1: g<16 (own h uint4-groups), kq<8 (8 kp each)
      int g = tid & 15, kq = tid >> 4;
      int kp0 = kq * 8;
      float4 a0 = {0,0,0,0}, a1 = a0, a2 = a0, a3 = a0;
#pragma unroll 4
      for (int i = 0; i < 8; ++i) {
        int kp = kp0 + i;
        uint4 w = tdhP4[kp * 64 + sh * 16 + g];
        uint32 d0 = drP[kp*4+0], d1 = drP[kp*4+1], d2 = drP[kp*4+2], d3 = drP[kp*4+3];
        a0.x = fdot2(d0,w.x,a0.x); a0.y = fdot2(d0,w.y,a0.y); a0.z = fdot2(d0,w.z,a0.z); a0.w = fdot2(d0,w.w,a0.w);
        a1.x = fdot2(d1,w.x,a1.x); a1.y = fdot2(d1,w.y,a1.y); a1.z = fdot2(d1,w.z,a1.z); a1.w = fdot2(d1,w.w,a1.w);
        a2.x = fdot2(d2,w.x,a2.x); a2.y = fdot2(d2,w.y,a2.y); a2.z = fdot2(d2,w.z,a2.z); a2.w = fdot2(d2,w.w,a2.w);
        a3.x = fdot2(d3,w.x,a3.x); a3.y = fdot2(d3,w.y,a3.y); a3.z = fdot2(d3,w.z,a3.z); a3.w = fdot2(d3,w.w,a3.w);
      }
      // region [0..2175], stride 68 f32 (17 float4) per slot (kq*4+r)
      ((float4*)scratch)[(kq*4+0)*17 + g] = a0;
      ((float4*)scratch)[(kq*4+1)*17 + g] = a1;
      ((float4*)scratch)[(kq*4+2)*17 + g] = a2;
      ((float4*)scratch)[(kq*4+3)*17 + g] = a3;
    } else if (tid < 256) {  // B2 alpha: g<8 (own d uint4-groups), kq<16
      int i0 = tid - 128, g = i0 & 7, kq = i0 >> 3;
      int kp0 = kq * 8;
      float4 a0 = {0,0,0,0}, a1 = a0, a2 = a0, a3 = a0;
#pragma unroll 4
      for (int i = 0; i < 8; ++i) {
        int kp = kp0 + i;
        uint4 w = wcP4[kp * 32 + sh * 8 + g];
        uint32 g0 = gxmP[kp*4+0], g1 = gxmP[kp*4+1], g2 = gxmP[kp*4+2], g3 = gxmP[kp*4+3];
        a0.x = fdot2(g0,w.x,a0.x); a0.y = fdot2(g0,w.y,a0.y); a0.z = fdot2(g0,w.z,a0.z); a0.w = fdot2(g0,w.w,a0.w);
        a1.x = fdot2(g1,w.x,a1.x); a1.y = fdot2(g1,w.y,a1.y); a1.z = fdot2(g1,w.z,a1.z); a1.w = fdot2(g1,w.w,a1.w);
        a2.x = fdot2(g2,w.x,a2.x); a2.y = fdot2(g2,w.y,a2.y); a2.z = fdot2(g2,w.z,a2.z); a2.w = fdot2(g2,w.w,a2.w);
        a3.x = fdot2(g3,w.x,a3.x); a3.y = fdot2(g3,w.y,a3.y); a3.z = fdot2(g3,w.z,a3.z); a3.w = fdot2(g3,w.w,a3.w);
      }
      // region [2304..4607], stride 36 f32 (9 float4) per slot
      ((float4*)(scratch + 2304))[(kq*4+0)*9 + g] = a0;
      ((float4*)(scratch + 2304))[(kq*4+1)*9 + g] = a1;
      ((float4*)(scratch + 2304))[(kq*4+2)*9 + g] = a2;
      ((float4*)(scratch + 2304))[(kq*4+3)*9 + g] = a3;
    }
    __syncthreads();

    // ---- C: reduce gamma_h -> own hd pairs ; reduce alpha -> post ----
    if (tid < 256) {
      int hl = tid & 63, r = tid >> 6;
      float ssum = tdhb_s[hl];
#pragma unroll
      for (int kq = 0; kq < 8; ++kq) ssum += scratch[(kq*4+r)*68 + hl];
      float hd = hf[r][hl] * __expf(-fmaxf(ssum, 0.f));
      int h = sh * 64 + hl, kp = h >> 1;
      ((unsigned short*)hdP)[(kp*4+r)*2 + (h & 1)] = f16u(hd);
    } else if (tid < 384) {
      int i0 = tid - 256, dl = i0 & 31, r = i0 >> 5;
      float ssum = wcb_s[sh*32 + dl];
#pragma unroll
      for (int kq = 0; kq < 16; ++kq) ssum += scratch[2304 + (kq*4+r)*36 + dl];
      al_s[r][sh*32 + dl] = ssum;
      __hip_atomic_store(mypU + 128 + r*32 + dl, __builtin_bit_cast(uint32, ssum),
                         __ATOMIC_RELAXED, __HIP_MEMORY_SCOPE_AGENT);
    }
    __syncthreads();

    // ---- D: x_h partials over OWN hd quarter | post hd payload ----
    if (tid < 512) {
      int g = tid & 31, kq = tid >> 5;  // kq<16, 2 kp each
      int kp0 = sh * 32 + kq * 2;
      float4 a0 = {0,0,0,0}, a1 = a0, a2 = a0, a3 = a0;
#pragma unroll
      for (int i = 0; i < 2; ++i) {
        int kp = kp0 + i;
        uint4 w = histP4[kp * 32 + g];
        uint32 h0 = hdP[kp*4+0], h1 = hdP[kp*4+1], h2 = hdP[kp*4+2], h3 = hdP[kp*4+3];
        a0.x = fdot2(h0,w.x,a0.x); a0.y = fdot2(h0,w.y,a0.y); a0.z = fdot2(h0,w.z,a0.z); a0.w = fdot2(h0,w.w,a0.w);
        a1.x = fdot2(h1,w.x,a1.x); a1.y = fdot2(h1,w.y,a1.y); a1.z = fdot2(h1,w.z,a1.z); a1.w = fdot2(h1,w.w,a1.w);
        a2.x = fdot2(h2,w.x,a2.x); a2.y = fdot2(h2,w.y,a2.y); a2.z = fdot2(h2,w.z,a2.z); a2.w = fdot2(h2,w.w,a2.w);
        a3.x = fdot2(h3,w.x,a3.x); a3.y = fdot2(h3,w.y,a3.y); a3.z = fdot2(h3,w.z,a3.z); a3.w = fdot2(h3,w.w,a3.w);
      }
      // region [0..8447], stride 132 f32 (33 float4) per slot (kq*4+r)
      ((float4*)scratch)[(kq*4+0)*33 + g] = a0;
      ((float4*)scratch)[(kq*4+1)*33 + g] = a1;
      ((float4*)scratch)[(kq*4+2)*33 + g] = a2;
      ((float4*)scratch)[(kq*4+3)*33 + g] = a3;
    } else if (tid < 640) {  // post own hd quarter
      int i0 = tid - 512, kpl = i0 >> 2, r = i0 & 3;
      uint32 v = hdP[(sh*32 + kpl)*4 + r];
      __hip_atomic_store(mypU + kpl*4 + r, v, __ATOMIC_RELAXED,
                         __HIP_MEMORY_SCOPE_AGENT);
    }
    __syncthreads();

    // ---- E0: reduce own x_h K-partial; post ----
    if (tid < 512) {
      int d = tid & 127, r = tid >> 7;
      float xo = 0.f;
#pragma unroll
      for (int kq = 0; kq < 16; ++kq) xo += scratch[(kq*4+r)*132 + d];
      xhp[sh][r][d] = xo;
      __hip_atomic_store(mypU + 256 + r*128 + d, __builtin_bit_cast(uint32, xo),
                         __ATOMIC_RELAXED, __HIP_MEMORY_SCOPE_AGENT);
    }
    __syncthreads();  // barrier drains vmcnt: all posts device-visible

    // ---- handshake: release own flag, spin on 3 partners ----
    if (tid == 0)
      __hip_atomic_store(flg + bid * 16, (unsigned)(t + 1), __ATOMIC_RELEASE,
                         __HIP_MEMORY_SCOPE_AGENT);
    if (tid < 3) {
      int ps = tid + (tid >= sh ? 1 : 0);
      unsigned* pfp = flg + (ps * 64 + grp) * 16;
      unsigned guard = 0;
      while (__hip_atomic_load(pfp, __ATOMIC_ACQUIRE,
                               __HIP_MEMORY_SCOPE_AGENT) < (unsigned)(t + 1)) {
        if (++guard > (1u << 22)) break;  // bounded: avoid hard hang
      }
    }
    __syncthreads();

    // ---- read 3 partner payloads ----
    if (tid < 768) {
      int p = tid >> 8, j = tid & 255;
      int ps = p + (p >= sh ? 1 : 0);
      const uint32* pq =
          (const uint32*)(exch + (size_t)((ps * 64 + grp) * 2 + (t & 1)) * 3072);
      uint32 v0 = __hip_atomic_load(pq + j, __ATOMIC_RELAXED, __HIP_MEMORY_SCOPE_AGENT);
      uint32 v1 = __hip_atomic_load(pq + 256 + j, __ATOMIC_RELAXED, __HIP_MEMORY_SCOPE_AGENT);
      uint32 v2 = __hip_atomic_load(pq + 512 + j, __ATOMIC_RELAXED, __HIP_MEMORY_SCOPE_AGENT);
      if (j < 128) {
        int kpl = j >> 2, r = j & 3;
        hdP[(ps*32 + kpl)*4 + r] = v0;
      } else {
        int i = j - 128, r = i >> 5, dl = i & 31;
        al_s[r][ps*32 + dl] = __builtin_bit_cast(float, v0);
      }
      int r1 = j >> 7, d1 = j & 127;
      xhp[ps][r1][d1] = __builtin_bit_cast(float, v1);
      xhp[ps][2 + r1][d1] = __builtin_bit_cast(float, v2);
    }
    __syncthreads();

    // ---- E1: x_h (fixed sum order: bitwise-identical across group), x_c ----
    if (tid < 512) {
      int d = tid & 127, r = tid >> 7;
      float xh = ((xhp[0][r][d] + xhp[1][r][d]) + (xhp[2][r][d] + xhp[3][r][d]))
                 + hb_s[d];
      xh_s[r][d] = xh;
      float mm = ms[r][d];
      float xc = mm * xs[r][d] + (1.f - mm) * xh;
      ((unsigned short*)xcP)[((d >> 1)*4 + r)*2 + (d & 1)] = f16u(xc);
    }
    __syncthreads();

    // ---- F: z partials (full D, r-shared weights) ----
    if (tid < 512) {
      int g = tid & 31, kq = tid >> 5;  // kq<16, 4 kp each
      int kp0 = kq * 4;
      float4 a0 = {0,0,0,0}, a1 = a0, a2 = a0, a3 = a0;
#pragma unroll
      for (int i = 0; i < 4; ++i) {
        int kp = kp0 + i;
        uint4 w = wfP4[kp * 32 + g];
        uint32 x0 = xcP[kp*4+0], x1 = xcP[kp*4+1], x2 = xcP[kp*4+2], x3 = xcP[kp*4+3];
        a0.x = fdot2(x0,w.x,a0.x); a0.y = fdot2(x0,w.y,a0.y); a0.z = fdot2(x0,w.z,a0.z); a0.w = fdot2(x0,w.w,a0.w);
        a1.x = fdot2(x1,w.x,a1.x); a1.y = fdot2(x1,w.y,a1.y); a1.z = fdot2(x1,w.z,a1.z); a1.w = fdot2(x1,w.w,a1.w);
        a2.x = fdot2(x2,w.x,a2.x); a2.y = fdot2(x2,w.y,a2.y); a2.z = fdot2(x2,w.z,a2.z); a2.w = fdot2(x2,w.w,a2.w);
        a3.x = fdot2(x3,w.x,a3.x); a3.y = fdot2(x3,w.y,a3.y); a3.z = fdot2(x3,w.z,a3.z); a3.w = fdot2(x3,w.w,a3.w);
      }
      ((float4*)scratch)[(kq*4+0)*33 + g] = a0;
      ((float4*)scratch)[(kq*4+1)*33 + g] = a1;
      ((float4*)scratch)[(kq*4+2)*33 + g] = a2;
      ((float4*)scratch)[(kq*4+3)*33 + g] = a3;
    }
    __syncthreads();

    // ---- G: c_h, c_c; out+loss only for own row (r==sh); pack [c_c|m] ----
    if (tid < 512) {
      int d = tid & 127, r = tid >> 7;
      float z = fb_s[d];
#pragma unroll
      for (int kq = 0; kq < 16; ++kq) z += scratch[(kq*4+r)*132 + d];
      float a = al_s[r][d], xh = xh_s[r][d];
      float ch = a * z + (1.f - a) * xh;
      float mm = ms[r][d], xv = xs[r][d];
      float cc = mm * xv + (1.f - mm) * ch;
      if (r == sh) {
        outp[base + (size_t)r * LD + d] = cc;
        lacc += (1.f - mm) * fabsf(ch - xv) * es[r][d] / den_s[t];
      }
      ((unsigned short*)cmP)[((d >> 1)*4 + r)*2 + (d & 1)] = f16u(cc);
      ((unsigned short*)cmP)[((64 + (d >> 1))*4 + r)*2 + (d & 1)] = f16u(mm);
    }
    __syncthreads();

    // ---- H: gate partials, own jj-quarter, 4 rows: jj=tid&63, kq=tid>>6 ----
    {
      int jj = tid & 63, kq = tid >> 6;  // kq<16, 8 kp each
      int jg = sh * 64 + jj, kp0 = kq * 8;
      const uint4* wp = (const uint4*)(wg + ((size_t)kp0 * 256 + jg) * 8);
      float a[4][4] = {};
#pragma unroll 4
      for (int i = 0; i < 8; ++i) {
        int kp = kp0 + i;
        uint4 wv = wp[0];
        uint4 wh = wp[1];
        wp += 512;
#pragma unroll
        for (int r = 0; r < 4; ++r) {
          uint32 c = cmP[kp*4 + r], h = hdP[kp*4 + r];
          a[r][0] = fdot2(c, wv.x, a[r][0]); a[r][1] = fdot2(c, wv.y, a[r][1]);
          a[r][2] = fdot2(c, wv.z, a[r][2]); a[r][3] = fdot2(c, wv.w, a[r][3]);
          a[r][0] = fdot2(h, wh.x, a[r][0]); a[r][1] = fdot2(h, wh.y, a[r][1]);
          a[r][2] = fdot2(h, wh.z, a[r][2]); a[r][3] = fdot2(h, wh.w, a[r][3]);
        }
      }
#pragma unroll
      for (int r = 0; r < 4; ++r)
#pragma unroll
        for (int q = 0; q < 4; ++q)
          scratch[(kq*16 + r*4 + q)*64 + jj] = a[r][q];
    }
    __syncthreads();

    // ---- I: reduce gates + LSTM (own jj-quarter, 4 rows) ----
    if (tid < 256) {
      int jj = tid & 63, r = tid >> 6;
      float g0 = bg_s[jj*4+0], g1 = bg_s[jj*4+1];
      float g2 = bg_s[jj*4+2], g3 = bg_s[jj*4+3];
#pragma unroll
      for (int kq = 0; kq < 16; ++kq) {
        int bix = (kq*16 + r*4)*64 + jj;
        g0 += scratch[bix]; g1 += scratch[bix + 64];
        g2 += scratch[bix + 128]; g3 += scratch[bix + 192];
      }
      float ig = 1.f / (1.f + __expf(-g0));
      float fg = 1.f / (1.f + __expf(-g1));
      float gg = tanhf(g2);
      float og = 1.f / (1.f + __expf(-g3));
      float c = fg * cst[r][jj] + ig * gg;
      cst[r][jj] = c;
      hf[r][jj] = og * tanhf(c);
    }
    __syncthreads();
  }

  // -------- loss reduce --------
  scratch[tid] = lacc;
  __syncthreads();
  for (int o = 512; o > 0; o >>= 1) {
    if (tid < o) scratch[tid] += scratch[tid + o];
    __syncthreads();
  }
  if (tid == 0) atomicAdd((float*)(wsb + OFF_LOSS), scratch[0]);
}

// ========================== K3: loss scalar =================================
__global__ void rits_fin(const char* __restrict__ wsb, float* __restrict__ outp) {
  if (threadIdx.x == 0 && blockIdx.x == 0)
    outp[(size_t)Bn * LD] = *((const float*)(wsb + OFF_LOSS));
}

// ============================== launcher ====================================
extern "C" void kernel_launch(void* const* d_in, const int* in_sizes, int n_in,
                              void* d_out, int out_size, void* d_ws,
                              size_t ws_size, hipStream_t stream) {
  const float* values = (const float*)d_in[0];
  const float* masks  = (const float*)d_in[1];
  const float* deltas = (const float*)d_in[2];
  const float* evalm  = (const float*)d_in[3];
  const float* td_h_W = (const float*)d_in[4];
  const float* td_h_b = (const float*)d_in[5];
  const float* td_x_w = (const float*)d_in[6];
  const float* td_x_b = (const float*)d_in[7];
  const float* hist_W = (const float*)d_in[8];
  const float* hist_b = (const float*)d_in[9];
  const float* feat_W = (const float*)d_in[10];
  const float* feat_b = (const float*)d_in[11];
  const float* wc_W   = (const float*)d_in[12];
  const float* wc_b   = (const float*)d_in[13];
  const float* W_ih   = (const float*)d_in[14];
  const float* W_hh   = (const float*)d_in[15];
  const float* b_ih   = (const float*)d_in[16];
  const float* b_hh   = (const float*)d_in[17];
  char* wsb = (char*)d_ws;
  float* outp = (float*)d_out;

  hipLaunchKernelGGL(rits_prep, dim3(1509), dim3(256), 0, stream, td_h_W,
                     hist_W, feat_W, wc_W, W_ih, W_hh, b_ih, b_hh, evalm, wsb);
  hipLaunchKernelGGL(rits_rec, dim3(256), dim3(1024), 0, stream, values, masks,
                     deltas, evalm, td_h_b, td_x_w, td_x_b, hist_b, feat_b,
                     wc_b, wsb, outp);
  hipLaunchKernelGGL(rits_fin, dim3(1), dim3(64), 0, stream, wsb, outp);
}

// Round 3
// 3693.341 us; speedup vs baseline: 1.3034x; 1.3034x over previous
//
#include <hip/hip_runtime.h>
#include <math.h>

// ---------------------------------------------------------------------------
// RITS forward, round 7: ON-CHIP-WEIGHT recurrence. 256 blocks x 512 threads.
// Theory from r0-r2: the step loop is latency-chain bound (per-step critical
// path of barrier-separated phases each waiting on L2 weight streams), not
// BW-bound. Fix: weights live on-chip for the whole kernel. 4-way h-split
// (64 groups x 4 blocks, 4 batch rows/group): per block gate-weight quarter
// (256KB) in VGPRs (128/thread), hist+wf FULL in LDS (96KB), tdh/wc quarters
// in VGPRs (16/thread). Step loop reads only LDS/regs + 8KB inputs + a 1KB
// hd/alpha exchange (x_h partials no longer exchanged: full hist per block
// -> each block computes identical full x_h locally). 9 barriers/step,
// conflict-free LDS patterns. B=256, L=256, D=128, H=256.
// ---------------------------------------------------------------------------

namespace {
constexpr int Bn = 256, Ln = 256, Dn = 128, Hn = 256;
constexpr long LD = (long)Ln * Dn;  // 32768

// ws byte offsets
constexpr int OFF_LOSS  = 0;
constexpr int OFF_DEN   = 256;      // 256 f32
constexpr int OFF_BIASG = 2048;     // 1024 f32 [jj][q]
constexpr int OFF_WG    = 8192;     // 262144 dw: [kp<128][jj<256][8]
                                    //   dw 0..3 = W_ih q0..3 pair kp, 4..7 = W_hh
constexpr int OFF_HISTP = 1056768;  // 16384 dw [kp<128][d<128]
constexpr int OFF_TDHP  = 1122304;  // 16384 dw [kp<64][h<256]
constexpr int OFF_WFP   = 1187840;  // 8192 dw  [kp<64][d<128] (diag=0)
constexpr int OFF_WCP   = 1220608;  // 16384 dw [kp<128][d<128]
constexpr int OFF_EXCH  = 1286144;  // 256 blk * 2 parity * 1024 B = 512 KB
constexpr int OFF_FLAG  = 1810432;  // 256 flags * 64 B
// exch payload (u32 idx): [0..127] = hd quarter [kpl<32][r<4]
//                         [128..255] = alpha quarter [r<4][dl<32]
}  // namespace

typedef _Float16 h2f __attribute__((ext_vector_type(2)));
typedef unsigned int uint32;

__device__ __forceinline__ float fdot2(uint32 a, uint32 b, float c) {
  return __builtin_amdgcn_fdot2(__builtin_bit_cast(h2f, a),
                                __builtin_bit_cast(h2f, b), c, false);
}
__device__ __forceinline__ uint32 packf16(float a, float b) {
  h2f p; p[0] = (_Float16)a; p[1] = (_Float16)b;
  return __builtin_bit_cast(uint32, p);
}

// ======================= K1: repack + biases + denom ========================
__global__ void rits_prep(const float* __restrict__ td_h_W,
                          const float* __restrict__ hist_W,
                          const float* __restrict__ feat_W,
                          const float* __restrict__ wc_W,
                          const float* __restrict__ W_ih,
                          const float* __restrict__ W_hh,
                          const float* __restrict__ b_ih,
                          const float* __restrict__ b_hh,
                          const float* __restrict__ evalm,
                          char* __restrict__ wsb) {
  const int blk = blockIdx.x, tid = threadIdx.x;
  if (blk < 1248) {
    int idx = blk * 256 + tid;
    if (idx < 262144) {  // wg
      int kp = idx >> 11, rem = idx & 2047, jj = rem >> 3, s8 = rem & 7;
      const float* src = (s8 < 4) ? W_ih : W_hh;
      int q = s8 & 3;
      const float* row = src + (size_t)(q * 256 + jj) * 256 + 2 * kp;
      ((uint32*)(wsb + OFF_WG))[idx] = packf16(row[0], row[1]);
    } else if (idx < 278528) {  // histP
      int i2 = idx - 262144, kp = i2 >> 7, d = i2 & 127;
      ((uint32*)(wsb + OFF_HISTP))[i2] =
          packf16(hist_W[d * 256 + 2 * kp], hist_W[d * 256 + 2 * kp + 1]);
    } else if (idx < 294912) {  // tdhP
      int i2 = idx - 278528, kp = i2 >> 8, h = i2 & 255;
      ((uint32*)(wsb + OFF_TDHP))[i2] =
          packf16(td_h_W[h * 128 + 2 * kp], td_h_W[h * 128 + 2 * kp + 1]);
    } else if (idx < 303104) {  // wfP: [kp<64][d<128], Wf[d][k], diag=0
      int i2 = idx - 294912, kp = i2 >> 7, d = i2 & 127;
      float a = (2 * kp == d) ? 0.f : feat_W[d * 128 + 2 * kp];
      float b = (2 * kp + 1 == d) ? 0.f : feat_W[d * 128 + 2 * kp + 1];
      ((uint32*)(wsb + OFF_WFP))[i2] = packf16(a, b);
    } else if (idx < 319488) {  // wcP
      int i2 = idx - 303104, kp = i2 >> 7, d = i2 & 127;
      ((uint32*)(wsb + OFF_WCP))[i2] =
          packf16(wc_W[d * 256 + 2 * kp], wc_W[d * 256 + 2 * kp + 1]);
    }
  } else if (blk < 1252) {  // biasg
    int i = (blk - 1248) * 256 + tid;
    int jj = i >> 2, q = i & 3;
    ((float*)(wsb + OFF_BIASG))[jj * 4 + q] =
        b_ih[q * 256 + jj] + b_hh[q * 256 + jj];
    if (blk == 1248 && tid == 0) *((float*)(wsb + OFF_LOSS)) = 0.f;
  } else if (blk < 1508) {  // denom per t
    int t = blk - 1252;
    __shared__ float red[256];
    int d = tid & 127, g = tid >> 7;
    float s = 0.f;
    for (int b = g; b < 256; b += 2) s += evalm[(size_t)b * LD + t * 128 + d];
    red[tid] = s;
    __syncthreads();
    for (int o = 128; o > 0; o >>= 1) {
      if (tid < o) red[tid] += red[tid + o];
      __syncthreads();
    }
    if (tid == 0) ((float*)(wsb + OFF_DEN))[t] = red[0] + 1e-5f;
  } else {  // blk == 1508: zero exchange flags (required each launch/replay)
    for (int i = tid; i < 4096; i += 256) ((uint32*)(wsb + OFF_FLAG))[i] = 0u;
  }
}

// ========================== K2: recurrent blocks ============================
__global__ __launch_bounds__(512, 2) void rits_rec(
    const float* __restrict__ values, const float* __restrict__ masks,
    const float* __restrict__ deltas, const float* __restrict__ evalm,
    const float* __restrict__ td_h_b, const float* __restrict__ td_x_w,
    const float* __restrict__ td_x_b, const float* __restrict__ hist_b,
    const float* __restrict__ feat_b, const float* __restrict__ wc_b,
    char* __restrict__ wsb, float* __restrict__ outp) {
  __shared__ uint32 histL[16384];                  // 64 KB  [kp<128][d<128]
  __shared__ uint32 wfL[8192];                     // 32 KB  [kp<64][d<128]
  __shared__ __align__(16) float scratch[4608];    // 18 KB shared partials
  __shared__ float al_s[4][128];
  __shared__ float hf[4][64], cst[4][64];          // own h-quarter, 4 rows
  __shared__ __align__(16) uint32 hdP[512];        // full hd pairs [kp][r]
  __shared__ __align__(16) uint32 cmP[512];        // [c_c | m] pairs [kp][r]
  __shared__ __align__(16) uint32 xcP[256];        // x_c pairs [kp][r]
  __shared__ __align__(16) uint32 drP[256];        // delta pairs [kp<64][r]
  __shared__ __align__(16) uint32 gxmP[512];       // [gamma_x | m] pairs
  __shared__ float bg_s[256];                      // [q][jj] quarter
  __shared__ float tdhb_s[64];
  __shared__ float txw_s[128], txb_s[128], hb_s[128], fb_s[128], wcb_s[128];

  const int tid = threadIdx.x;
  const int bid = blockIdx.x;
  const int sh = bid >> 6;    // owned h/jj quarter 0..3
  const int grp = bid & 63;   // group: rows 4*grp..4*grp+3
  const size_t b0 = (size_t)grp * 4;
  const uint32* wg = (const uint32*)(wsb + OFF_WG);
  const uint32* tdhG = (const uint32*)(wsb + OFF_TDHP);
  const uint32* wcG = (const uint32*)(wsb + OFF_WCP);
  const float* denG = (const float*)(wsb + OFF_DEN);
  char* exch = wsb + OFF_EXCH;
  unsigned int* flg = (unsigned int*)(wsb + OFF_FLAG);

  // -------- LDS weight preload (one-time) --------
  {
    const uint4* hG = (const uint4*)(wsb + OFF_HISTP);
#pragma unroll
    for (int k = 0; k < 8; ++k) ((uint4*)histL)[k * 512 + tid] = hG[k * 512 + tid];
    const uint4* fG = (const uint4*)(wsb + OFF_WFP);
#pragma unroll
    for (int k = 0; k < 4; ++k) ((uint4*)wfL)[k * 512 + tid] = fG[k * 512 + tid];
  }
  // -------- small tables + state init --------
  if (tid < 256) {  // bg as [q][jj]
    bg_s[tid] = ((const float*)(wsb + OFF_BIASG))[(sh * 64 + (tid & 63)) * 4 + (tid >> 6)];
  } else if (tid < 320) tdhb_s[tid - 256] = td_h_b[sh * 64 + (tid - 256)];
  else if (tid < 448) txw_s[tid - 320] = td_x_w[tid - 320];
  if (tid < 128) txb_s[tid] = td_x_b[tid];
  else if (tid < 256) hb_s[tid - 128] = hist_b[tid - 128];
  else if (tid < 384) fb_s[tid - 256] = feat_b[tid - 256];
  else wcb_s[tid - 384] = wc_b[tid - 384];
  if (tid < 256) ((float*)hf)[tid] = 0.f;
  else ((float*)cst)[tid - 256] = 0.f;

  // -------- per-thread role indices --------
  const int dA = tid & 127, rA = tid >> 7;          // A/D/F mapping
  const int hlB = tid & 63, kqB = (tid >> 6) & 7;   // B-tdh mapping
  const int dlB = tid & 31, kqA = tid >> 5;         // B-alpha mapping (0..15)
  const int jjH = tid & 63, qhH = (tid >> 6) & 1, kqH = tid >> 7;  // H (0..3)
  const int jg = sh * 64 + jjH;

  // -------- register weight preload (one-time) --------
  uint2 wv_[32], wh_[32];   // gate weights: 32 kp x (2 q) x {v,h} = 128 VGPR
#pragma unroll
  for (int i = 0; i < 32; ++i) {
    const uint32* p = wg + ((size_t)((kqH * 32 + i) * 256 + jg)) * 8 + 2 * qhH;
    wv_[i] = *(const uint2*)p;
    wh_[i] = *(const uint2*)(p + 4);
  }
  uint32 tw[8];             // tdh quarter: [kqB*8+i][own hl]
#pragma unroll
  for (int i = 0; i < 8; ++i) tw[i] = tdhG[(kqB * 8 + i) * 256 + sh * 64 + hlB];
  uint32 cw[8];             // wc quarter: [kqA*8+i][own dl]
#pragma unroll
  for (int i = 0; i < 8; ++i) cw[i] = wcG[(kqA * 8 + i) * 128 + sh * 32 + dlB];
  __syncthreads();

  float lacc = 0.f;
  for (int t = 0; t < Ln; ++t) {
    const size_t base = b0 * LD + (size_t)t * 128;
    uint32* mypU = (uint32*)(exch + (size_t)(bid * 2 + (t & 1)) * 1024);

    // ---- A: inputs -> regs; delta/gamma_x/m pairs -> LDS ----
    const size_t gi = base + (size_t)rA * LD + dA;
    const float xv = values[gi];
    const float mv = masks[gi];
    const float ev = evalm[gi];
    {
      const size_t gb = base + (size_t)rA * LD;
      if (dA < 64) {
        float d0v = deltas[gb + 2 * dA], d1v = deltas[gb + 2 * dA + 1];
        drP[dA * 4 + rA] = packf16(d0v, d1v);
        float g0 = __expf(-fmaxf(fmaf(d0v, txw_s[2 * dA], txb_s[2 * dA]), 0.f));
        float g1 = __expf(-fmaxf(fmaf(d1v, txw_s[2 * dA + 1], txb_s[2 * dA + 1]), 0.f));
        gxmP[dA * 4 + rA] = packf16(g0, g1);
      } else {
        int k2 = dA - 64;
        gxmP[dA * 4 + rA] = packf16(masks[gb + 2 * k2], masks[gb + 2 * k2 + 1]);
      }
    }
    __syncthreads();

    // ---- B: tdh partials (reg weights) + alpha partials (reg weights) ----
    {
      float ga0 = 0.f, ga1 = 0.f, ga2 = 0.f, ga3 = 0.f;
#pragma unroll
      for (int i = 0; i < 8; ++i) {
        uint4 d4 = *(const uint4*)&drP[(kqB * 8 + i) * 4];
        ga0 = fdot2(d4.x, tw[i], ga0); ga1 = fdot2(d4.y, tw[i], ga1);
        ga2 = fdot2(d4.z, tw[i], ga2); ga3 = fdot2(d4.w, tw[i], ga3);
      }
      scratch[2304 + (kqB * 4 + 0) * 68 + hlB] = ga0;
      scratch[2304 + (kqB * 4 + 1) * 68 + hlB] = ga1;
      scratch[2304 + (kqB * 4 + 2) * 68 + hlB] = ga2;
      scratch[2304 + (kqB * 4 + 3) * 68 + hlB] = ga3;
      float aa0 = 0.f, aa1 = 0.f, aa2 = 0.f, aa3 = 0.f;
#pragma unroll
      for (int i = 0; i < 8; ++i) {
        uint4 g4 = *(const uint4*)&gxmP[(kqA * 8 + i) * 4];
        aa0 = fdot2(g4.x, cw[i], aa0); aa1 = fdot2(g4.y, cw[i], aa1);
        aa2 = fdot2(g4.z, cw[i], aa2); aa3 = fdot2(g4.w, cw[i], aa3);
      }
      scratch[(kqA * 4 + 0) * 36 + dlB] = aa0;
      scratch[(kqA * 4 + 1) * 36 + dlB] = aa1;
      scratch[(kqA * 4 + 2) * 36 + dlB] = aa2;
      scratch[(kqA * 4 + 3) * 36 + dlB] = aa3;
    }
    __syncthreads();

    // ---- C: hd (own quarter) -> hdP + post; alpha (own quarter) + post ----
    if (tid < 256) {
      int hl = tid & 63, r = tid >> 6;
      float s = tdhb_s[hl];
#pragma unroll
      for (int kq = 0; kq < 8; ++kq) s += scratch[2304 + (kq * 4 + r) * 68 + hl];
      float hd = hf[r][hl] * __expf(-fmaxf(s, 0.f));
      float hdo = __shfl_down(hd, 1);
      if (!(hl & 1)) {
        uint32 pv = packf16(hd, hdo);
        int kpl = hl >> 1;
        hdP[(sh * 32 + kpl) * 4 + r] = pv;
        __hip_atomic_store(mypU + kpl * 4 + r, pv, __ATOMIC_RELAXED,
                           __HIP_MEMORY_SCOPE_AGENT);
      }
    } else if (tid < 384) {
      int i0 = tid - 256, dl = i0 & 31, r = i0 >> 5;
      float s = wcb_s[sh * 32 + dl];
#pragma unroll
      for (int kq = 0; kq < 16; ++kq) s += scratch[(kq * 4 + r) * 36 + dl];
      al_s[r][sh * 32 + dl] = s;
      __hip_atomic_store(mypU + 128 + r * 32 + dl,
                         __builtin_bit_cast(uint32, s),
                         __ATOMIC_RELAXED, __HIP_MEMORY_SCOPE_AGENT);
    }
    __syncthreads();  // drains vmcnt: posts device-visible

    // ---- handshake ----
    if (tid == 0)
      __hip_atomic_store(flg + bid * 16, (unsigned)(t + 1), __ATOMIC_RELEASE,
                         __HIP_MEMORY_SCOPE_AGENT);
    if (tid < 3) {
      int ps = tid + (tid >= sh ? 1 : 0);
      unsigned* pfp = flg + (ps * 64 + grp) * 16;
      unsigned guard = 0;
      while (__hip_atomic_load(pfp, __ATOMIC_ACQUIRE,
                               __HIP_MEMORY_SCOPE_AGENT) < (unsigned)(t + 1)) {
        if (++guard > (1u << 24)) break;  // bounded: avoid hard hang
      }
    }
    __syncthreads();

    // ---- readback: 3 partner payloads (hd quarters + alpha quarters) ----
    if (tid < 256) {
#pragma unroll
      for (int p = 0; p < 3; ++p) {
        int ps = p + (p >= sh ? 1 : 0);
        const uint32* pq =
            (const uint32*)(exch + (size_t)((ps * 64 + grp) * 2 + (t & 1)) * 1024);
        uint32 v = __hip_atomic_load(pq + tid, __ATOMIC_RELAXED,
                                     __HIP_MEMORY_SCOPE_AGENT);
        if (tid < 128) hdP[ps * 128 + tid] = v;
        else {
          int i = tid - 128;
          al_s[i >> 5][ps * 32 + (i & 31)] = __builtin_bit_cast(float, v);
        }
      }
    }
    __syncthreads();

    // ---- D: full x_h per (d,r) from full hdP (LDS hist); x_c; pack ----
    float xhv;
    {
      float xh = hb_s[dA];
#pragma unroll 16
      for (int kp = 0; kp < 128; ++kp)
        xh = fdot2(hdP[kp * 4 + rA], histL[kp * 128 + dA], xh);
      xhv = xh;
      float xc = mv * xv + (1.f - mv) * xh;
      float xco = __shfl_down(xc, 1);
      if (!(dA & 1)) xcP[((dA >> 1)) * 4 + rA] = packf16(xc, xco);
    }
    __syncthreads();

    // ---- F: z per (d,r) (LDS wf); c_h, c_c, out, loss; pack [c_c|m] ----
    {
      float z = fb_s[dA];
#pragma unroll 16
      for (int kp = 0; kp < 64; ++kp)
        z = fdot2(xcP[kp * 4 + rA], wfL[kp * 128 + dA], z);
      float a = al_s[rA][dA];
      float ch = a * z + (1.f - a) * xhv;
      float cc = mv * xv + (1.f - mv) * ch;
      if (rA == sh) {
        outp[base + (size_t)rA * LD + dA] = cc;
        lacc += (1.f - mv) * fabsf(ch - xv) * ev / denG[t];
      }
      float cco = __shfl_down(cc, 1);
      float mmo = __shfl_down(mv, 1);
      if (!(dA & 1)) {
        cmP[(dA >> 1) * 4 + rA] = packf16(cc, cco);
        cmP[(64 + (dA >> 1)) * 4 + rA] = packf16(mv, mmo);
      }
    }
    __syncthreads();

    // ---- H: gate partials (reg weights): (jj, qh, kq), 32 kp each ----
    {
      float a00 = 0.f, a01 = 0.f, a02 = 0.f, a03 = 0.f;  // q' = 0
      float a10 = 0.f, a11 = 0.f, a12 = 0.f, a13 = 0.f;  // q' = 1
#pragma unroll
      for (int i = 0; i < 32; ++i) {
        int kp = kqH * 32 + i;
        uint4 c4 = *(const uint4*)&cmP[kp * 4];
        uint4 h4 = *(const uint4*)&hdP[kp * 4];
        a00 = fdot2(c4.x, wv_[i].x, a00); a10 = fdot2(c4.x, wv_[i].y, a10);
        a00 = fdot2(h4.x, wh_[i].x, a00); a10 = fdot2(h4.x, wh_[i].y, a10);
        a01 = fdot2(c4.y, wv_[i].x, a01); a11 = fdot2(c4.y, wv_[i].y, a11);
        a01 = fdot2(h4.y, wh_[i].x, a01); a11 = fdot2(h4.y, wh_[i].y, a11);
        a02 = fdot2(c4.z, wv_[i].x, a02); a12 = fdot2(c4.z, wv_[i].y, a12);
        a02 = fdot2(h4.z, wh_[i].x, a02); a12 = fdot2(h4.z, wh_[i].y, a12);
        a03 = fdot2(c4.w, wv_[i].x, a03); a13 = fdot2(c4.w, wv_[i].y, a13);
        a03 = fdot2(h4.w, wh_[i].x, a03); a13 = fdot2(h4.w, wh_[i].y, a13);
      }
      const int q0 = 2 * qhH, q1 = 2 * qhH + 1;
      scratch[(kqH * 16 + 0 * 4 + q0) * 64 + jjH] = a00;
      scratch[(kqH * 16 + 1 * 4 + q0) * 64 + jjH] = a01;
      scratch[(kqH * 16 + 2 * 4 + q0) * 64 + jjH] = a02;
      scratch[(kqH * 16 + 3 * 4 + q0) * 64 + jjH] = a03;
      scratch[(kqH * 16 + 0 * 4 + q1) * 64 + jjH] = a10;
      scratch[(kqH * 16 + 1 * 4 + q1) * 64 + jjH] = a11;
      scratch[(kqH * 16 + 2 * 4 + q1) * 64 + jjH] = a12;
      scratch[(kqH * 16 + 3 * 4 + q1) * 64 + jjH] = a13;
    }
    __syncthreads();

    // ---- I: reduce gates + LSTM (own jj-quarter, 4 rows) ----
    if (tid < 256) {
      int jj = tid & 63, r = tid >> 6;
      float g0 = bg_s[0 * 64 + jj], g1 = bg_s[1 * 64 + jj];
      float g2 = bg_s[2 * 64 + jj], g3 = bg_s[3 * 64 + jj];
#pragma unroll
      for (int kq = 0; kq < 4; ++kq) {
        int bx = (kq * 16 + r * 4) * 64 + jj;
        g0 += scratch[bx]; g1 += scratch[bx + 64];
        g2 += scratch[bx + 128]; g3 += scratch[bx + 192];
      }
      float ig = 1.f / (1.f + __expf(-g0));
      float fg = 1.f / (1.f + __expf(-g1));
      float gg = tanhf(g2);
      float og = 1.f / (1.f + __expf(-g3));
      float c = fg * cst[r][jj] + ig * gg;
      cst[r][jj] = c;
      hf[r][jj] = og * tanhf(c);
    }
    __syncthreads();
  }

  // -------- loss reduce --------
  scratch[tid] = lacc;
  __syncthreads();
  for (int o = 256; o > 0; o >>= 1) {
    if (tid < o) scratch[tid] += scratch[tid + o];
    __syncthreads();
  }
  if (tid == 0) atomicAdd((float*)(wsb + OFF_LOSS), scratch[0]);
}

// ========================== K3: loss scalar =================================
__global__ void rits_fin(const char* __restrict__ wsb, float* __restrict__ outp) {
  if (threadIdx.x == 0 && blockIdx.x == 0)
    outp[(size_t)Bn * LD] = *((const float*)(wsb + OFF_LOSS));
}

// ============================== launcher ====================================
extern "C" void kernel_launch(void* const* d_in, const int* in_sizes, int n_in,
                              void* d_out, int out_size, void* d_ws,
                              size_t ws_size, hipStream_t stream) {
  const float* values = (const float*)d_in[0];
  const float* masks  = (const float*)d_in[1];
  const float* deltas = (const float*)d_in[2];
  const float* evalm  = (const float*)d_in[3];
  const float* td_h_W = (const float*)d_in[4];
  const float* td_h_b = (const float*)d_in[5];
  const float* td_x_w = (const float*)d_in[6];
  const float* td_x_b = (const float*)d_in[7];
  const float* hist_W = (const float*)d_in[8];
  const float* hist_b = (const float*)d_in[9];
  const float* feat_W = (const float*)d_in[10];
  const float* feat_b = (const float*)d_in[11];
  const float* wc_W   = (const float*)d_in[12];
  const float* wc_b   = (const float*)d_in[13];
  const float* W_ih   = (const float*)d_in[14];
  const float* W_hh   = (const float*)d_in[15];
  const float* b_ih   = (const float*)d_in[16];
  const float* b_hh   = (const float*)d_in[17];
  char* wsb = (char*)d_ws;
  float* outp = (float*)d_out;

  hipLaunchKernelGGL(rits_prep, dim3(1509), dim3(256), 0, stream, td_h_W,
                     hist_W, feat_W, wc_W, W_ih, W_hh, b_ih, b_hh, evalm, wsb);
  hipLaunchKernelGGL(rits_rec, dim3(256), dim3(512), 0, stream, values, masks,
                     deltas, evalm, td_h_b, td_x_w, td_x_b, hist_b, feat_b,
                     wc_b, wsb, outp);
  hipLaunchKernelGGL(rits_fin, dim3(1), dim3(64), 0, stream, wsb, outp);
}